// Round 1
// baseline (269.544 us; speedup 1.0000x reference)
//
#include <hip/hip_runtime.h>
#include <math.h>

#define B_    32
#define F_    4000
#define L_    65
#define N_    129           // 2L-1, odd irfft length
#define HOP_  64
#define K_    192           // hop + 2L - 2
#define GF_   8             // frames per wave
#define WAVES_ 4
#define OUTLEN_ ((F_-1)*HOP_ + K_)   // 256128
#define GAIN_ 0.01f
#define BLKS_PER_B_ (F_/(GF_*WAVES_))   // 125

// Math notes (derived from the reference):
//  ir_raw[t] = (1/129)(X0 + 2*sum_{k=1..64} X[k] cos(2*pi*k*t/129)), even: ir_raw[t]=ir_raw[129-t]
//  roll by 64:  ir_rolled[m] = ir_raw[|m-64|]
//  ir[m] = win[m]*ir_rolled[m],  win[m]=0.5(1-cos(2*pi*m/129)) (win[0]=0)
//  frames[k] = GAIN * sum_{j=0..63} (2*noise[j]-1) * ir[k-j]   (exact linear conv, K=192)
//  OLA: out[b, 64*f + k] += frames[k]

__global__ __launch_bounds__(256, 2) void filtered_noise_kernel(
    const float* __restrict__ nfilt,   // [B,F,65]
    const float* __restrict__ noise,   // [B,F,64]
    float* __restrict__ out)           // [B, OUTLEN]
{
    __shared__ float costab[N_];
    __shared__ float irp[WAVES_][260];  // padded: [0,64)=0, [64,192]=ir, (192,..]=0

    const int tid  = threadIdx.x;
    const int lane = tid & 63;
    const int wid  = __builtin_amdgcn_readfirstlane(tid >> 6);

    // cos(2*pi*i/129) table (double-precision arg, once per block)
    for (int i = tid; i < N_; i += 256)
        costab[i] = (float)cos((double)i * (2.0 * M_PI / 129.0));

    float* ir = irp[wid];
    for (int i = lane; i < 260; i += 64) ir[i] = 0.0f;

    __syncthreads();

    const int b  = blockIdx.x / BLKS_PER_B_;
    const int g  = (blockIdx.x % BLKS_PER_B_) * WAVES_ + wid;  // group in [0,500)
    const int f0 = g * GF_;

    const int   t     = lane + 1;            // this lane computes ir_raw[t], t=1..64
    const float scale = 2.0f / 129.0f;
    const float cA = 0.5f * (1.0f - costab[64 - t]) * scale;   // win[64-t] * (2/129)
    const float cB = 0.5f * (1.0f - costab[64 + t]) * scale;   // win[64+t] * (2/129)
    const float c0 = 0.5f * (1.0f - costab[64]) * scale;       // win[64]   * (2/129)

    float acc[GF_ + 2];
    #pragma unroll
    for (int u = 0; u < GF_ + 2; ++u) acc[u] = 0.0f;

    #pragma unroll
    for (int i = 0; i < GF_; ++i) {
        const int f = f0 + i;
        const float* Xf = nfilt + (size_t)(b * F_ + f) * L_;   // wave-uniform ptr
        const float* Zf = noise + (size_t)(b * F_ + f) * HOP_; // wave-uniform ptr

        // Phase A: a = 0.5*X0 + sum_{k>=1} X[k]*cos(2*pi*k*t/129);  s = 0.5*X0 + sum X[k]
        float x0 = Xf[0];
        float a  = 0.5f * x0;
        float s  = 0.5f * x0;
        int jdx = 0;
        #pragma unroll 8
        for (int k = 1; k < L_; ++k) {
            jdx += t;
            jdx = (jdx >= N_) ? (jdx - N_) : jdx;
            float x = Xf[k];                 // wave-uniform -> s_load
            a = fmaf(x, costab[jdx], a);
            s += x;
        }
        // windowed linear-phase IR into padded LDS buffer
        ir[128 - t] = cA * a;                // m = 64-t
        ir[128 + t] = cB * a;                // m = 64+t
        if (lane == 0) ir[128] = c0 * s;     // m = 64 (ir_raw[0])
        __syncthreads();

        // Phase B: conv — lane owns k = lane, lane+64, lane+128
        #pragma unroll 4
        for (int j = 0; j < HOP_; ++j) {
            float nj = fmaf(2.0f, Zf[j], -1.0f);   // wave-uniform
            const float* p = ir + (64 + lane - j); // pad zeros handle bounds
            acc[i]     = fmaf(nj, p[0],   acc[i]);
            acc[i + 1] = fmaf(nj, p[64],  acc[i + 1]);
            acc[i + 2] = fmaf(nj, p[128], acc[i + 2]);
        }
        __syncthreads();
    }

    // Epilogue: slots 2..GF-1 are exclusive to this wave (plain store);
    // boundary slots overlap the neighbor group (atomic into zeroed out).
    const size_t obase = (size_t)b * OUTLEN_ + (size_t)f0 * HOP_ + lane;
    #pragma unroll
    for (int u = 0; u < GF_ + 2; ++u) {
        float v = acc[u] * GAIN_;
        size_t p = obase + (size_t)u * 64;
        if (u >= 2 && u < GF_) out[p] = v;
        else atomicAdd(out + p, v);
    }
}

extern "C" void kernel_launch(void* const* d_in, const int* in_sizes, int n_in,
                              void* d_out, int out_size, void* d_ws, size_t ws_size,
                              hipStream_t stream) {
    const float* nfilt = (const float*)d_in[0];
    const float* noise = (const float*)d_in[1];
    float* out = (float*)d_out;

    hipMemsetAsync(d_out, 0, (size_t)out_size * sizeof(float), stream);

    dim3 grid(B_ * BLKS_PER_B_);   // 4000 blocks
    dim3 block(256);
    filtered_noise_kernel<<<grid, block, 0, stream>>>(nfilt, noise, out);
}

// Round 3
// 251.041 us; speedup vs baseline: 1.0737x; 1.0737x over previous
//
#include <hip/hip_runtime.h>
#include <math.h>

#define B_    32
#define F_    4000
#define L_    65
#define N_    129           // 2L-1, odd irfft length
#define HOP_  64
#define K_    192           // hop + 2L - 2
#define GF_   8             // frames per wave
#define WAVES_ 4
#define OUTLEN_ ((F_-1)*HOP_ + K_)   // 256128
#define GAIN_ 0.01f
#define BLKS_PER_B_ (F_/(GF_*WAVES_))   // 125

// Math notes (derived from the reference):
//  ir_raw[t] = (1/129)(X0 + 2*sum_{k=1..64} X[k] cos(2*pi*k*t/129)), even symmetric
//  roll by 64:  ir_rolled[m] = ir_raw[|m-64|]
//  ir[m] = win[m]*ir_rolled[m],  win[m]=0.5(1-cos(2*pi*m/129))
//  frames[k] = GAIN * sum_{j=0..63} (2*noise[j]-1) * ir[k-j]  (exact linear conv)
//  OLA: out[b, 64*f + k] += frames[k]
//
// R3 delta vs R1 (single change): Phase A cos(k*t*theta) computed by Chebyshev
// recurrence c_{k+1} = 2c1*c_k - c_{k-1} (3 VALU/k, no LDS gather), reseeded
// from the exact costab every 16 steps. Kills the 2.0e7-cycle
// SQ_LDS_BANK_CONFLICT from the strided costab[(t*k)%129] gather.
// Error bound: |U_m| <= 1/sin(theta_min) ~ 41, 16 steps * eps * 41 ~ 8e-5 in c,
// attenuated by win*(2/129)*GAIN -> ~1e-5 in out vs 2e-4 threshold.

__global__ __launch_bounds__(256, 2) void filtered_noise_kernel(
    const float* __restrict__ nfilt,   // [B,F,65]
    const float* __restrict__ noise,   // [B,F,64]
    float* __restrict__ out)           // [B, OUTLEN]
{
    __shared__ float costab[N_];
    __shared__ float irp[WAVES_][260];  // padded: [0,64)=0, [64,192]=ir, (192,..]=0

    const int tid  = threadIdx.x;
    const int lane = tid & 63;
    const int wid  = __builtin_amdgcn_readfirstlane(tid >> 6);

    // cos(2*pi*i/129) table (double-precision arg, once per block)
    for (int i = tid; i < N_; i += 256)
        costab[i] = (float)cos((double)i * (2.0 * M_PI / 129.0));

    float* ir = irp[wid];
    for (int i = lane; i < 260; i += 64) ir[i] = 0.0f;

    __syncthreads();

    const int b  = blockIdx.x / BLKS_PER_B_;
    const int g  = (blockIdx.x % BLKS_PER_B_) * WAVES_ + wid;  // group in [0,500)
    const int f0 = g * GF_;

    const int   t     = lane + 1;            // this lane computes ir_raw[t], t=1..64
    const float scale = 2.0f / 129.0f;
    const float cA = 0.5f * (1.0f - costab[64 - t]) * scale;   // win[64-t] * (2/129)
    const float cB = 0.5f * (1.0f - costab[64 + t]) * scale;   // win[64+t] * (2/129)
    const float c0 = 0.5f * (1.0f - costab[64]) * scale;       // win[64]   * (2/129)

    // Chebyshev seeds from the exact table (per-lane, once)
    const float c1 = costab[t];
    const float tc = 2.0f * c1;
    float sA[4], sB[4];
    sA[0] = 1.0f;                 sB[0] = c1;
    sA[1] = costab[(16*t) % N_];  sB[1] = costab[(17*t) % N_];
    sA[2] = costab[(32*t) % N_];  sB[2] = costab[(33*t) % N_];
    sA[3] = costab[(48*t) % N_];  sB[3] = costab[(49*t) % N_];

    float acc[GF_ + 2];
    #pragma unroll
    for (int u = 0; u < GF_ + 2; ++u) acc[u] = 0.0f;

    #pragma unroll
    for (int i = 0; i < GF_; ++i) {
        const int f = f0 + i;
        const float* Xf = nfilt + (size_t)(b * F_ + f) * L_;   // wave-uniform ptr
        const float* Zf = noise + (size_t)(b * F_ + f) * HOP_; // wave-uniform ptr

        // Phase A: a = 0.5*X0 + sum_{k=1..64} X[k]*cos(k*t*theta0);  s = 0.5*X0 + sum X[k]
        float x0 = Xf[0];
        float a  = 0.5f * x0;
        float s  = 0.5f * x0;
        #pragma unroll
        for (int c = 0; c < 4; ++c) {
            float ckm1 = sA[c], ck = sB[c];   // cos(16c*t*th), cos((16c+1)*t*th)
            #pragma unroll
            for (int q = 0; q < 16; ++q) {
                float x = Xf[c * 16 + q + 1];     // wave-uniform -> s_load
                a = fmaf(x, ck, a);
                s += x;
                float cn = fmaf(tc, ck, -ckm1);   // Chebyshev step
                ckm1 = ck; ck = cn;
            }
        }
        // windowed linear-phase IR into padded LDS buffer
        ir[128 - t] = cA * a;                // m = 64-t
        ir[128 + t] = cB * a;                // m = 64+t
        if (lane == 0) ir[128] = c0 * s;     // m = 64 (ir_raw[0])
        __syncthreads();

        // Phase B: conv — lane owns k = lane, lane+64, lane+128
        #pragma unroll 4
        for (int j = 0; j < HOP_; ++j) {
            float nj = fmaf(2.0f, Zf[j], -1.0f);   // wave-uniform
            const float* p = ir + (64 + lane - j); // pad zeros handle bounds
            acc[i]     = fmaf(nj, p[0],   acc[i]);
            acc[i + 1] = fmaf(nj, p[64],  acc[i + 1]);
            acc[i + 2] = fmaf(nj, p[128], acc[i + 2]);
        }
        __syncthreads();
    }

    // Epilogue: slots 2..GF-1 are exclusive to this wave (plain store);
    // boundary slots overlap the neighbor group (atomic into zeroed out).
    const size_t obase = (size_t)b * OUTLEN_ + (size_t)f0 * HOP_ + lane;
    #pragma unroll
    for (int u = 0; u < GF_ + 2; ++u) {
        float v = acc[u] * GAIN_;
        size_t p = obase + (size_t)u * 64;
        if (u >= 2 && u < GF_) out[p] = v;
        else atomicAdd(out + p, v);
    }
}

extern "C" void kernel_launch(void* const* d_in, const int* in_sizes, int n_in,
                              void* d_out, int out_size, void* d_ws, size_t ws_size,
                              hipStream_t stream) {
    const float* nfilt = (const float*)d_in[0];
    const float* noise = (const float*)d_in[1];
    float* out = (float*)d_out;

    hipMemsetAsync(d_out, 0, (size_t)out_size * sizeof(float), stream);

    dim3 grid(B_ * BLKS_PER_B_);   // 4000 blocks
    dim3 block(256);
    filtered_noise_kernel<<<grid, block, 0, stream>>>(nfilt, noise, out);
}

// Round 4
// 247.038 us; speedup vs baseline: 1.0911x; 1.0162x over previous
//
#include <hip/hip_runtime.h>
#include <math.h>

#define B_    32
#define F_    4000
#define L_    65
#define N_    129           // 2L-1, odd irfft length
#define HOP_  64
#define K_    192           // hop + 2L - 2
#define GF_   8             // frames per wave
#define WAVES_ 4
#define OUTLEN_ ((F_-1)*HOP_ + K_)   // 256128
#define GAIN_ 0.01f
#define BLKS_PER_B_ (F_/(GF_*WAVES_))   // 125

// Math notes (derived from the reference):
//  ir_raw[t] = (1/129)(X0 + 2*sum_{k=1..64} X[k] cos(2*pi*k*t/129)), even symmetric
//  roll by 64:  ir_rolled[m] = ir_raw[|m-64|]
//  ir[m] = win[m]*ir_rolled[m],  win[m]=0.5(1-cos(2*pi*m/129))
//  frames[k] = GAIN * sum_{j=0..63} (2*noise[j]-1) * ir[k-j]  (exact linear conv)
//  OLA: out[b, 64*f + k] += frames[k]
//
// R4 delta vs R3 (single change): removed the two in-loop __syncthreads().
// The ir buffer is per-wave (irp[wid]); same-wave DS ops execute in order and
// the compiler preserves write->read order on the same __shared__ array and
// inserts lgkmcnt waits before data use. R3 counters showed stall-bound
// (VALUBusy 55%, no pipe saturated): 16 block barriers x 4-wave skew was the
// remaining sink.

__global__ __launch_bounds__(256, 2) void filtered_noise_kernel(
    const float* __restrict__ nfilt,   // [B,F,65]
    const float* __restrict__ noise,   // [B,F,64]
    float* __restrict__ out)           // [B, OUTLEN]
{
    __shared__ float costab[N_];
    __shared__ float irp[WAVES_][260];  // padded: [0,64)=0, [64,192]=ir, (192,..]=0

    const int tid  = threadIdx.x;
    const int lane = tid & 63;
    const int wid  = __builtin_amdgcn_readfirstlane(tid >> 6);

    // cos(2*pi*i/129) table (double-precision arg, once per block)
    for (int i = tid; i < N_; i += 256)
        costab[i] = (float)cos((double)i * (2.0 * M_PI / 129.0));

    float* ir = irp[wid];
    for (int i = lane; i < 260; i += 64) ir[i] = 0.0f;

    __syncthreads();   // costab + pad init; the only block barrier

    const int b  = blockIdx.x / BLKS_PER_B_;
    const int g  = (blockIdx.x % BLKS_PER_B_) * WAVES_ + wid;  // group in [0,500)
    const int f0 = g * GF_;

    const int   t     = lane + 1;            // this lane computes ir_raw[t], t=1..64
    const float scale = 2.0f / 129.0f;
    const float cA = 0.5f * (1.0f - costab[64 - t]) * scale;   // win[64-t] * (2/129)
    const float cB = 0.5f * (1.0f - costab[64 + t]) * scale;   // win[64+t] * (2/129)
    const float c0 = 0.5f * (1.0f - costab[64]) * scale;       // win[64]   * (2/129)

    // Chebyshev seeds from the exact table (per-lane, once)
    const float c1 = costab[t];
    const float tc = 2.0f * c1;
    float sA[4], sB[4];
    sA[0] = 1.0f;                 sB[0] = c1;
    sA[1] = costab[(16*t) % N_];  sB[1] = costab[(17*t) % N_];
    sA[2] = costab[(32*t) % N_];  sB[2] = costab[(33*t) % N_];
    sA[3] = costab[(48*t) % N_];  sB[3] = costab[(49*t) % N_];

    float acc[GF_ + 2];
    #pragma unroll
    for (int u = 0; u < GF_ + 2; ++u) acc[u] = 0.0f;

    #pragma unroll
    for (int i = 0; i < GF_; ++i) {
        const int f = f0 + i;
        const float* Xf = nfilt + (size_t)(b * F_ + f) * L_;   // wave-uniform ptr
        const float* Zf = noise + (size_t)(b * F_ + f) * HOP_; // wave-uniform ptr

        // Phase A: a = 0.5*X0 + sum_{k=1..64} X[k]*cos(k*t*theta0);  s = 0.5*X0 + sum X[k]
        float x0 = Xf[0];
        float a  = 0.5f * x0;
        float s  = 0.5f * x0;
        #pragma unroll
        for (int c = 0; c < 4; ++c) {
            float ckm1 = sA[c], ck = sB[c];   // cos(16c*t*th), cos((16c+1)*t*th)
            #pragma unroll
            for (int q = 0; q < 16; ++q) {
                float x = Xf[c * 16 + q + 1];     // wave-uniform -> s_load
                a = fmaf(x, ck, a);
                s += x;
                float cn = fmaf(tc, ck, -ckm1);   // Chebyshev step
                ckm1 = ck; ck = cn;
            }
        }
        // windowed linear-phase IR into padded per-wave LDS buffer.
        // Same-wave DS ordering + compiler-inserted lgkmcnt waits make this
        // safe without a block barrier (buffer is private to this wave).
        ir[128 - t] = cA * a;                // m = 64-t
        ir[128 + t] = cB * a;                // m = 64+t
        if (lane == 0) ir[128] = c0 * s;     // m = 64 (ir_raw[0])

        // Phase B: conv — lane owns k = lane, lane+64, lane+128
        #pragma unroll 4
        for (int j = 0; j < HOP_; ++j) {
            float nj = fmaf(2.0f, Zf[j], -1.0f);   // wave-uniform
            const float* p = ir + (64 + lane - j); // pad zeros handle bounds
            acc[i]     = fmaf(nj, p[0],   acc[i]);
            acc[i + 1] = fmaf(nj, p[64],  acc[i + 1]);
            acc[i + 2] = fmaf(nj, p[128], acc[i + 2]);
        }
    }

    // Epilogue: slots 2..GF-1 are exclusive to this wave (plain store);
    // boundary slots overlap the neighbor group (atomic into zeroed out).
    const size_t obase = (size_t)b * OUTLEN_ + (size_t)f0 * HOP_ + lane;
    #pragma unroll
    for (int u = 0; u < GF_ + 2; ++u) {
        float v = acc[u] * GAIN_;
        size_t p = obase + (size_t)u * 64;
        if (u >= 2 && u < GF_) out[p] = v;
        else atomicAdd(out + p, v);
    }
}

extern "C" void kernel_launch(void* const* d_in, const int* in_sizes, int n_in,
                              void* d_out, int out_size, void* d_ws, size_t ws_size,
                              hipStream_t stream) {
    const float* nfilt = (const float*)d_in[0];
    const float* noise = (const float*)d_in[1];
    float* out = (float*)d_out;

    hipMemsetAsync(d_out, 0, (size_t)out_size * sizeof(float), stream);

    dim3 grid(B_ * BLKS_PER_B_);   // 4000 blocks
    dim3 block(256);
    filtered_noise_kernel<<<grid, block, 0, stream>>>(nfilt, noise, out);
}

// Round 5
// 243.845 us; speedup vs baseline: 1.1054x; 1.0131x over previous
//
#include <hip/hip_runtime.h>
#include <math.h>

#define B_    32
#define F_    4000
#define L_    65
#define N_    129           // 2L-1, odd irfft length
#define HOP_  64
#define K_    192           // hop + 2L - 2
#define GF_   8             // frames per wave
#define WAVES_ 4
#define OUTLEN_ ((F_-1)*HOP_ + K_)   // 256128
#define GAIN_ 0.01f
#define BLKS_PER_B_ (F_/(GF_*WAVES_))   // 125

// Math notes (derived from the reference):
//  ir_raw[t] = (1/129)(X0 + 2*sum_{k=1..64} X[k] cos(2*pi*k*t/129)), even symmetric
//  ir[m] = win[m]*ir_raw[|m-64|],  win[m]=0.5(1-cos(2*pi*m/129))
//  frames[k] = GAIN * sum_{j=0..63} (2*noise[j]-1) * ir[k-j]  (exact linear conv)
//  OLA: out[b, 64*f + k] += frames[k]
//
// R5 delta vs R4 (latency attack — R4 counters showed waves stalled ~90% of
// lifetime at 40% occupancy):
//  1. Per-wave DOUBLE-BUFFERED ir + software pipeline: Phase A of frame i+1
//     (pure VALU Chebyshev) is computed before Phase B of frame i, filling
//     B's LDS-latency shadow. Double buffer removes the WAR hazard that
//     serialized A(i+1) behind B(i).
//  2. Phase A's a/s accumulators split into 4 independent partials (one per
//     Chebyshev reseed segment): serial chain 256 cy -> 64 cy per frame.

__global__ __launch_bounds__(256, 2) void filtered_noise_kernel(
    const float* __restrict__ nfilt,   // [B,F,65]
    const float* __restrict__ noise,   // [B,F,64]
    float* __restrict__ out)           // [B, OUTLEN]
{
    __shared__ float costab[N_];
    __shared__ float irp[WAVES_][2][260]; // per-wave dbuf: [0,64)=0,[64,192]=ir,(192..)=0

    const int tid  = threadIdx.x;
    const int lane = tid & 63;
    const int wid  = __builtin_amdgcn_readfirstlane(tid >> 6);

    for (int i = tid; i < N_; i += 256)
        costab[i] = (float)cos((double)i * (2.0 * M_PI / 129.0));

    // zero both per-wave buffers (pads must be 0; middle gets overwritten)
    for (int i = lane; i < 520; i += 64) irp[wid][0][i] = 0.0f;  // [0] and [1] contiguous

    __syncthreads();   // costab + pad init; the only block barrier

    const int b  = blockIdx.x / BLKS_PER_B_;
    const int g  = (blockIdx.x % BLKS_PER_B_) * WAVES_ + wid;  // group in [0,500)
    const int f0 = g * GF_;

    const int   t     = lane + 1;            // this lane computes ir_raw[t], t=1..64
    const float scale = 2.0f / 129.0f;
    const float cA = 0.5f * (1.0f - costab[64 - t]) * scale;   // win[64-t] * (2/129)
    const float cB = 0.5f * (1.0f - costab[64 + t]) * scale;   // win[64+t] * (2/129)
    const float c0 = 0.5f * (1.0f - costab[64]) * scale;       // win[64]   * (2/129)

    // Chebyshev seeds from the exact table (per-lane, once)
    const float c1 = costab[t];
    const float tc = 2.0f * c1;
    float sA[4], sB[4];
    sA[0] = 1.0f;                 sB[0] = c1;
    sA[1] = costab[(16*t) % N_];  sB[1] = costab[(17*t) % N_];
    sA[2] = costab[(32*t) % N_];  sB[2] = costab[(33*t) % N_];
    sA[3] = costab[(48*t) % N_];  sB[3] = costab[(49*t) % N_];

    const float* Xbase = nfilt + (size_t)(b * F_ + f0) * L_;
    const float* Zbase = noise + (size_t)(b * F_ + f0) * HOP_;

    // Phase A for frame idx -> windowed IR into irb (per-wave buffer).
    // 4 independent partial chains (one per reseed segment) for a and s.
    auto phaseA = [&](int idx, float* irb) {
        const float* Xf = Xbase + idx * L_;            // wave-uniform ptr
        float x0 = Xf[0];
        float a0 = 0.5f * x0, a1 = 0.f, a2 = 0.f, a3 = 0.f;
        float s0 = 0.5f * x0, s1 = 0.f, s2 = 0.f, s3 = 0.f;
        float ap[4] = {0.f, 0.f, 0.f, 0.f};
        float sp[4] = {0.f, 0.f, 0.f, 0.f};
        #pragma unroll
        for (int c = 0; c < 4; ++c) {
            float ckm1 = sA[c], ck = sB[c];   // cos(16c*t*th), cos((16c+1)*t*th)
            float aa = 0.f, ss = 0.f;
            #pragma unroll
            for (int q = 0; q < 16; ++q) {
                float x = Xf[c * 16 + q + 1];     // wave-uniform -> s_load
                aa = fmaf(x, ck, aa);
                ss += x;
                float cn = fmaf(tc, ck, -ckm1);   // Chebyshev step
                ckm1 = ck; ck = cn;
            }
            ap[c] = aa; sp[c] = ss;
        }
        float a = ((a0 + ap[0]) + ap[1]) + (ap[2] + ap[3]);
        float s = ((s0 + sp[0]) + sp[1]) + (sp[2] + sp[3]);
        (void)a1; (void)a2; (void)a3; (void)s1; (void)s2; (void)s3;
        irb[128 - t] = cA * a;                // m = 64-t
        irb[128 + t] = cB * a;                // m = 64+t
        if (lane == 0) irb[128] = c0 * s;     // m = 64 (ir_raw[0])
    };

    float acc[GF_ + 2];
    #pragma unroll
    for (int u = 0; u < GF_ + 2; ++u) acc[u] = 0.0f;

    phaseA(0, irp[wid][0]);   // prologue: fill buffer 0

    #pragma unroll
    for (int i = 0; i < GF_; ++i) {
        // Pipeline: next frame's Phase A (VALU) issued ahead of this frame's
        // Phase B (LDS reads) — scheduler fills LDS latency with Chebyshev.
        if (i < GF_ - 1) phaseA(i + 1, irp[wid][(i + 1) & 1]);

        const float* ir = irp[wid][i & 1];
        const float* Zf = Zbase + i * HOP_;            // wave-uniform ptr

        // Phase B: conv — lane owns k = lane, lane+64, lane+128
        #pragma unroll 4
        for (int j = 0; j < HOP_; ++j) {
            float nj = fmaf(2.0f, Zf[j], -1.0f);   // wave-uniform
            const float* p = ir + (64 + lane - j); // pad zeros handle bounds
            acc[i]     = fmaf(nj, p[0],   acc[i]);
            acc[i + 1] = fmaf(nj, p[64],  acc[i + 1]);
            acc[i + 2] = fmaf(nj, p[128], acc[i + 2]);
        }
    }

    // Epilogue: slots 2..GF-1 are exclusive to this wave (plain store);
    // boundary slots overlap the neighbor group (atomic into zeroed out).
    const size_t obase = (size_t)b * OUTLEN_ + (size_t)f0 * HOP_ + lane;
    #pragma unroll
    for (int u = 0; u < GF_ + 2; ++u) {
        float v = acc[u] * GAIN_;
        size_t p = obase + (size_t)u * 64;
        if (u >= 2 && u < GF_) out[p] = v;
        else atomicAdd(out + p, v);
    }
}

extern "C" void kernel_launch(void* const* d_in, const int* in_sizes, int n_in,
                              void* d_out, int out_size, void* d_ws, size_t ws_size,
                              hipStream_t stream) {
    const float* nfilt = (const float*)d_in[0];
    const float* noise = (const float*)d_in[1];
    float* out = (float*)d_out;

    hipMemsetAsync(d_out, 0, (size_t)out_size * sizeof(float), stream);

    dim3 grid(B_ * BLKS_PER_B_);   // 4000 blocks
    dim3 block(256);
    filtered_noise_kernel<<<grid, block, 0, stream>>>(nfilt, noise, out);
}

// Round 7
// 232.573 us; speedup vs baseline: 1.1590x; 1.0485x over previous
//
#include <hip/hip_runtime.h>
#include <math.h>

typedef float v2f __attribute__((ext_vector_type(2)));

#define B_    32
#define F_    4000
#define L_    65
#define N_    129           // 2L-1, odd irfft length
#define HOP_  64
#define K_    192           // hop + 2L - 2
#define GF_   8             // frames per wave
#define WAVES_ 4
#define OUTLEN_ ((F_-1)*HOP_ + K_)   // 256128
#define GAIN_ 0.01f
#define BLKS_PER_B_ (F_/(GF_*WAVES_))   // 125

// Math (see earlier rounds): ir[m]=win[m]*ir_raw[|m-64|]; frames = conv(2n-1, ir);
// OLA hop 64. Phase A: Chebyshev cosine recurrence, reseeded every 16 from table.
//
// R7 delta vs R6 (correctness fix, structure kept): R6's absmax 4e-3 came from
// the compiler sinking the upper-half ir writes (ir[129+lane]) below Phase B
// reads — per-lane alias analysis proves THIS lane's write never hits THIS
// lane's constant-offset reads, but the RAW is CROSS-LANE through LDS.
// __builtin_amdgcn_sched_barrier(0) pins program order (zero instructions);
// the per-wave in-order DS pipe then guarantees cross-lane visibility.
// (Implication: R4/R5's barrier-free scheme passed by scheduling luck only.)

__global__ __launch_bounds__(256, 2) void filtered_noise_kernel(
    const float* __restrict__ nfilt,   // [B,F,65]
    const float* __restrict__ noise,   // [B,F,64]
    float* __restrict__ out)           // [B, OUTLEN]
{
    __shared__ float costab[N_];
    __shared__ float irp[WAVES_][260];  // per-wave: [0,64)=0, [64,192]=ir, (192..)=0

    const int tid  = threadIdx.x;
    const int lane = tid & 63;
    const int wid  = __builtin_amdgcn_readfirstlane(tid >> 6);

    for (int i = tid; i < N_; i += 256)
        costab[i] = (float)cos((double)i * (2.0 * M_PI / 129.0));

    float* ir = irp[wid];
    for (int i = lane; i < 260; i += 64) ir[i] = 0.0f;

    __syncthreads();   // costab + pad init; the only block barrier

    const int b  = blockIdx.x / BLKS_PER_B_;
    const int g  = (blockIdx.x % BLKS_PER_B_) * WAVES_ + wid;  // group in [0,500)
    const int f0 = g * GF_;

    const int   t     = lane + 1;            // lane computes ir_raw[t], t=1..64
    const float scale = 2.0f / 129.0f;
    const float cA = 0.5f * (1.0f - costab[64 - t]) * scale;   // win[64-t]*(2/129)
    const float cB = 0.5f * (1.0f - costab[64 + t]) * scale;   // win[64+t]*(2/129)
    const float c0 = 0.5f * (1.0f - costab[64]) * scale;       // win[64]  *(2/129)

    // Chebyshev seeds from the exact table (per-lane, once)
    const float c1 = costab[t];
    const float tc = 2.0f * c1;
    float sdA[4], sdB[4];
    sdA[0] = 1.0f;                 sdB[0] = c1;
    sdA[1] = costab[(16*t) % N_];  sdB[1] = costab[(17*t) % N_];
    sdA[2] = costab[(32*t) % N_];  sdB[2] = costab[(33*t) % N_];
    sdA[3] = costab[(48*t) % N_];  sdB[3] = costab[(49*t) % N_];

    const float* Xf = nfilt + (size_t)(b * F_ + f0) * L_;          // uniform
    const float* Zf = noise + (size_t)(b * F_ + f0) * HOP_ + lane; // per-lane
    float*       op = out + (size_t)b * OUTLEN_ + (size_t)f0 * HOP_ + lane;

    const float* pb = ir + lane;   // fixed DS base; offsets are compile-time

    // rolling accumulators: wab = {slot i, slot i+1}, wc = slot i+2
    v2f wab = {0.0f, 0.0f};
    float wc = 0.0f;

    #pragma unroll 1
    for (int i = 0; i < GF_; ++i) {
        // coalesced per-lane noise load for this frame (vmcnt; latency hidden
        // behind Phase A). nj precompute folded here: zc = 2*noise-1.
        float zc = Zf[0];
        zc = fmaf(2.0f, zc, -1.0f);

        // ---- Phase A: a = 0.5*X0 + sum_{k=1..64} X[k]*cos(k*t*th) ----
        float x0 = Xf[0];
        float a = 0.5f * x0;
        float s = 0.5f * x0;
        #pragma unroll
        for (int c = 0; c < 4; ++c) {
            float ckm1 = sdA[c], ck = sdB[c];
            float aa = 0.0f, ss = 0.0f;
            #pragma unroll
            for (int q = 0; q < 16; ++q) {
                float x = Xf[c * 16 + q + 1];     // wave-uniform -> s_load
                aa = fmaf(x, ck, aa);
                ss += x;
                float cn = fmaf(tc, ck, -ckm1);   // Chebyshev step
                ckm1 = ck; ck = cn;
            }
            a += aa; s += ss;
        }

        // ---- windowed IR -> per-wave LDS; order pinned around the writes.
        // Cross-lane RAW: sched_barrier(0) forbids compiler motion; the DS
        // pipe is in-order per wave, so program order = execution order.
        __builtin_amdgcn_sched_barrier(0);
        ir[128 - t] = cA * a;
        ir[128 + t] = cB * a;
        if (lane == 0) ir[128] = c0 * s;
        __builtin_amdgcn_sched_barrier(0);

        // ---- Phase B: DS-pure conv; lane owns k = lane, lane+64, lane+128 ----
        #pragma unroll
        for (int j = 0; j < HOP_; ++j) {
            float njs = __uint_as_float(
                __builtin_amdgcn_readlane(__float_as_uint(zc), j));
            v2f njv = {njs, njs};
            v2f pv  = {pb[64 - j], pb[128 - j]};   // ds_read2, const offsets
            wab = njv * pv + wab;                  // v_pk_fma_f32 (contract)
            wc  = fmaf(njs, pb[192 - j], wc);
        }
        __builtin_amdgcn_sched_barrier(0);   // WAR fence vs next frame's writes

        // ---- retire slot i (i<2 overlaps previous group -> atomic) ----
        float v = wab.x * GAIN_;
        if (i < 2) atomicAdd(op, v); else *op = v;
        op += HOP_;
        wab.x = wab.y; wab.y = wc; wc = 0.0f;
        Xf += L_; Zf += HOP_;
    }
    atomicAdd(op, wab.x * GAIN_);          // slot 8 (overlaps next group)
    atomicAdd(op + HOP_, wab.y * GAIN_);   // slot 9
}

extern "C" void kernel_launch(void* const* d_in, const int* in_sizes, int n_in,
                              void* d_out, int out_size, void* d_ws, size_t ws_size,
                              hipStream_t stream) {
    const float* nfilt = (const float*)d_in[0];
    const float* noise = (const float*)d_in[1];
    float* out = (float*)d_out;

    hipMemsetAsync(d_out, 0, (size_t)out_size * sizeof(float), stream);

    dim3 grid(B_ * BLKS_PER_B_);   // 4000 blocks
    dim3 block(256);
    filtered_noise_kernel<<<grid, block, 0, stream>>>(nfilt, noise, out);
}